// Round 2
// baseline (630.057 us; speedup 1.0000x reference)
//
#include <hip/hip_runtime.h>
#include <hip/hip_bf16.h>

#define B_   8
#define N_   8192
#define S_   2048
#define D1_  128
#define D2_  256
#define CIN_ 384
#define C1_  256
#define C2_  128
#define ROWS_ (B_ * N_)   // 65536

// ---------------------------------------------------------------------------
// 3-nearest-neighbor search, replicating the reference's expanded-form
// distance  d = (|x1|^2 - 2 x1.x2) + |x2|^2  in f32 with no fma contraction,
// strict `<` updates => stable tie-break (lower index wins), matching top_k.
// ---------------------------------------------------------------------------
__global__ __launch_bounds__(256) void nn3_kernel(
    const float* __restrict__ xyz1, const float* __restrict__ xyz2,
    int* __restrict__ nidx, float* __restrict__ nw)
{
#pragma clang fp contract(off)
    __shared__ float sx[S_], sy[S_], sz[S_], sr[S_];
    const int b = blockIdx.y;
    const int n = blockIdx.x * 256 + threadIdx.x;
    const float* x2 = xyz2 + (size_t)b * S_ * 3;
    for (int i = threadIdx.x; i < S_; i += 256) {
        float a = x2[i * 3 + 0], c = x2[i * 3 + 1], d = x2[i * 3 + 2];
        sx[i] = a; sy[i] = c; sz[i] = d;
        sr[i] = (a * a + c * c) + d * d;
    }
    __syncthreads();
    const float* p = xyz1 + ((size_t)b * N_ + n) * 3;
    const float px = p[0], py = p[1], pz = p[2];
    const float r1 = (px * px + py * py) + pz * pz;
    float d1 = 3.4e38f, d2 = 3.4e38f, d3 = 3.4e38f;
    int i1 = 0, i2 = 0, i3 = 0;
    for (int s = 0; s < S_; ++s) {
        float dot = (px * sx[s] + py * sy[s]) + pz * sz[s];
        float d = (r1 - 2.0f * dot) + sr[s];
        if (d < d3) {
            if (d < d2) {
                d3 = d2; i3 = i2;
                if (d < d1) { d2 = d1; i2 = i1; d1 = d; i1 = s; }
                else        { d2 = d;  i2 = s; }
            } else { d3 = d; i3 = s; }
        }
    }
    float ra = 1.0f / (d1 + 1e-8f);
    float rb = 1.0f / (d2 + 1e-8f);
    float rc = 1.0f / (d3 + 1e-8f);
    float sum = (ra + rb) + rc;
    size_t o = ((size_t)b * N_ + n) * 3;
    nidx[o + 0] = i1; nidx[o + 1] = i2; nidx[o + 2] = i3;
    nw[o + 0] = ra / sum; nw[o + 1] = rb / sum; nw[o + 2] = rc / sum;
}

// ---------------------------------------------------------------------------
// Weighted gather: interp[row][c] = sum_k w_k * points2[b][idx_k][c]
// ---------------------------------------------------------------------------
__global__ __launch_bounds__(256) void interp_kernel(
    const float* __restrict__ p2, const int* __restrict__ nidx,
    const float* __restrict__ nw, float* __restrict__ interp)
{
    const int row = blockIdx.x;          // 0..65535
    const int c = threadIdx.x;           // 0..255
    const int b = row >> 13;             // N_=8192
    const int i0 = nidx[row * 3 + 0], i1 = nidx[row * 3 + 1], i2 = nidx[row * 3 + 2];
    const float w0 = nw[row * 3 + 0], w1 = nw[row * 3 + 1], w2 = nw[row * 3 + 2];
    const float* base = p2 + (size_t)b * S_ * D2_;
    float v = base[(size_t)i0 * D2_ + c] * w0
            + base[(size_t)i1 * D2_ + c] * w1
            + base[(size_t)i2 * D2_ + c] * w2;
    interp[(size_t)row * D2_ + c] = v;
}

// src[R][C] -> dst[C][R]
__global__ void transpose_kernel(const float* __restrict__ src,
                                 float* __restrict__ dst, int R, int Cc)
{
    int i = blockIdx.x * blockDim.x + threadIdx.x;
    if (i < R * Cc) {
        int r = i / Cc, c = i % Cc;
        dst[c * R + r] = src[i];
    }
}

// ---------------------------------------------------------------------------
// fp32 tiled GEMM: C[row][o] = sum_k A[row][k] * Bt[k][o] + bias[o]
// MODE 0: A = concat(points1[row][0:128], interp[row][0:256])
// MODE 1: A = relu(y1[row][k] * scale[k] + shift[k])   (BN+ReLU fused on load)
// ---------------------------------------------------------------------------
#define BM 128
#define BN_T 128
#define KT 16

template <int MODE>
__global__ __launch_bounds__(256) void gemm_kernel(
    const float* __restrict__ A1, const float* __restrict__ A2,
    const float* __restrict__ Bt, const float* __restrict__ bias,
    const float* __restrict__ scale, const float* __restrict__ shift,
    float* __restrict__ Cc, int K, int Cout)
{
    __shared__ float As[KT][BM + 4];
    __shared__ float Bs[KT][BN_T];
    const int tid = threadIdx.x;
    const int row0 = blockIdx.x * BM;
    const int col0 = blockIdx.y * BN_T;
    const int ty = tid / 16, tx = tid % 16;
    const int la_row = tid / 4;            // 0..63
    const int la_k = (tid % 4) * 4;        // 0,4,8,12
    const int lb_k = tid / 32;             // 0..7
    const int lb_o = (tid % 32) * 4;       // 0..124

    float acc[8][8];
#pragma unroll
    for (int i = 0; i < 8; ++i)
#pragma unroll
        for (int j = 0; j < 8; ++j) acc[i][j] = 0.0f;

    for (int k0 = 0; k0 < K; k0 += KT) {
#pragma unroll
        for (int pp = 0; pp < 2; ++pp) {
            int r = row0 + la_row + pp * 64;
            int kk = k0 + la_k;
            float4 v;
            if (MODE == 0) {
                if (kk < D1_) v = *(const float4*)(A1 + (size_t)r * D1_ + kk);
                else          v = *(const float4*)(A2 + (size_t)r * D2_ + (kk - D1_));
            } else {
                v = *(const float4*)(A1 + (size_t)r * C1_ + kk);
                float4 sc = *(const float4*)(scale + kk);
                float4 sh = *(const float4*)(shift + kk);
                v.x = fmaxf(fmaf(v.x, sc.x, sh.x), 0.0f);
                v.y = fmaxf(fmaf(v.y, sc.y, sh.y), 0.0f);
                v.z = fmaxf(fmaf(v.z, sc.z, sh.z), 0.0f);
                v.w = fmaxf(fmaf(v.w, sc.w, sh.w), 0.0f);
            }
            As[la_k + 0][la_row + pp * 64] = v.x;
            As[la_k + 1][la_row + pp * 64] = v.y;
            As[la_k + 2][la_row + pp * 64] = v.z;
            As[la_k + 3][la_row + pp * 64] = v.w;
        }
#pragma unroll
        for (int pp = 0; pp < 2; ++pp) {
            int kk = k0 + lb_k + pp * 8;
            *(float4*)&Bs[lb_k + pp * 8][lb_o] =
                *(const float4*)(Bt + (size_t)kk * Cout + col0 + lb_o);
        }
        __syncthreads();
#pragma unroll
        for (int kk = 0; kk < KT; ++kk) {
            float a[8], b[8];
            *(float4*)(a + 0) = *(const float4*)&As[kk][ty * 8 + 0];
            *(float4*)(a + 4) = *(const float4*)&As[kk][ty * 8 + 4];
            *(float4*)(b + 0) = *(const float4*)&Bs[kk][tx * 8 + 0];
            *(float4*)(b + 4) = *(const float4*)&Bs[kk][tx * 8 + 4];
#pragma unroll
            for (int i = 0; i < 8; ++i)
#pragma unroll
                for (int j = 0; j < 8; ++j)
                    acc[i][j] = fmaf(a[i], b[j], acc[i][j]);
        }
        __syncthreads();
    }
    const int o0 = col0 + tx * 8;
    float4 b0 = *(const float4*)(bias + o0);
    float4 b1v = *(const float4*)(bias + o0 + 4);
#pragma unroll
    for (int i = 0; i < 8; ++i) {
        size_t r = (size_t)(row0 + ty * 8 + i);
        float4 v0 = { acc[i][0] + b0.x, acc[i][1] + b0.y, acc[i][2] + b0.z, acc[i][3] + b0.w };
        float4 v1 = { acc[i][4] + b1v.x, acc[i][5] + b1v.y, acc[i][6] + b1v.z, acc[i][7] + b1v.w };
        *(float4*)(Cc + r * Cout + o0) = v0;
        *(float4*)(Cc + r * Cout + o0 + 4) = v1;
    }
}

// per-channel sum / sumsq partials + atomics
__global__ __launch_bounds__(256) void stats_kernel(
    const float* __restrict__ y, float* __restrict__ sums,
    float* __restrict__ ssqs, int C, int rowsPerBlock)
{
    const int c = threadIdx.x % C;
    const int rOff = threadIdx.x / C;
    const int stride = blockDim.x / C;
    const int r0 = blockIdx.x * rowsPerBlock;
    float s = 0.0f, q = 0.0f;
    for (int r = r0 + rOff; r < r0 + rowsPerBlock; r += stride) {
        float v = y[(size_t)r * C + c];
        s += v; q += v * v;
    }
    atomicAdd(&sums[c], s);
    atomicAdd(&ssqs[c], q);
}

__global__ void finalize_kernel(const float* __restrict__ sums,
                                const float* __restrict__ ssqs,
                                const float* __restrict__ g,
                                const float* __restrict__ be,
                                float* __restrict__ scale,
                                float* __restrict__ shift, int C, float invCnt)
{
    int c = threadIdx.x;
    if (c < C) {
        float mu = sums[c] * invCnt;
        float var = ssqs[c] * invCnt - mu * mu;
        float sc = g[c] / sqrtf(var + 1e-5f);
        scale[c] = sc;
        shift[c] = be[c] - mu * sc;
    }
}

// final BN+ReLU, store FLOAT32 (reference output dtype is float32)
__global__ __launch_bounds__(256) void bnrelu_store_kernel(
    const float* __restrict__ y, const float* __restrict__ scale,
    const float* __restrict__ shift, float* __restrict__ out)
{
    int i = blockIdx.x * 256 + threadIdx.x;   // one float4 per thread
    float4 v = ((const float4*)y)[i];
    int o = (i * 4) & (C2_ - 1);
    float4 sc = *(const float4*)(scale + o);
    float4 sh = *(const float4*)(shift + o);
    float4 r;
    r.x = fmaxf(fmaf(v.x, sc.x, sh.x), 0.0f);
    r.y = fmaxf(fmaf(v.y, sc.y, sh.y), 0.0f);
    r.z = fmaxf(fmaf(v.z, sc.z, sh.z), 0.0f);
    r.w = fmaxf(fmaf(v.w, sc.w, sh.w), 0.0f);
    ((float4*)out)[i] = r;
}

extern "C" void kernel_launch(void* const* d_in, const int* in_sizes, int n_in,
                              void* d_out, int out_size, void* d_ws, size_t ws_size,
                              hipStream_t stream)
{
    const float* xyz1    = (const float*)d_in[0];
    const float* xyz2    = (const float*)d_in[1];
    const float* points1 = (const float*)d_in[2];
    const float* points2 = (const float*)d_in[3];
    const float* w1  = (const float*)d_in[4];
    const float* b1  = (const float*)d_in[5];
    const float* g1  = (const float*)d_in[6];
    const float* be1 = (const float*)d_in[7];
    const float* w2  = (const float*)d_in[8];
    const float* b2  = (const float*)d_in[9];
    const float* g2  = (const float*)d_in[10];
    const float* be2 = (const float*)d_in[11];
    float* out = (float*)d_out;

    float* interp = (float*)d_ws;                     // ROWS_*C1_ floats (64MB)
    float* y1     = interp + (size_t)ROWS_ * C1_;     // ROWS_*C1_ floats (64MB)
    int*   nidx   = (int*)(y1 + (size_t)ROWS_ * C1_); // ROWS_*3
    float* nw     = (float*)(nidx + ROWS_ * 3);       // ROWS_*3
    float* w1t    = nw + ROWS_ * 3;                   // 384*256
    float* w2t    = w1t + CIN_ * C1_;                 // 256*128
    float* sum1   = w2t + C1_ * C2_;                  // 256
    float* ssq1   = sum1 + 256;                       // 256
    float* sum2   = ssq1 + 256;                       // 128
    float* ssq2   = sum2 + 128;                       // 128
    float* scale1 = ssq2 + 128;                       // 256
    float* shift1 = scale1 + 256;                     // 256
    float* scale2 = shift1 + 256;                     // 128
    float* shift2 = scale2 + 128;                     // 128
    float* y2     = interp;                           // reuse (gemm1 consumed it)

    hipMemsetAsync(sum1, 0, (256 + 256 + 128 + 128) * sizeof(float), stream);

    transpose_kernel<<<dim3((C1_ * CIN_ + 255) / 256), 256, 0, stream>>>(w1, w1t, C1_, CIN_);
    transpose_kernel<<<dim3((C2_ * C1_ + 255) / 256), 256, 0, stream>>>(w2, w2t, C2_, C1_);

    nn3_kernel<<<dim3(N_ / 256, B_), 256, 0, stream>>>(xyz1, xyz2, nidx, nw);
    interp_kernel<<<dim3(ROWS_), 256, 0, stream>>>(points2, nidx, nw, interp);

    gemm_kernel<0><<<dim3(ROWS_ / BM, C1_ / BN_T), 256, 0, stream>>>(
        points1, interp, w1t, b1, nullptr, nullptr, y1, CIN_, C1_);
    stats_kernel<<<dim3(256), 256, 0, stream>>>(y1, sum1, ssq1, C1_, ROWS_ / 256);
    finalize_kernel<<<1, 256, 0, stream>>>(sum1, ssq1, g1, be1, scale1, shift1, C1_, 1.0f / ROWS_);

    gemm_kernel<1><<<dim3(ROWS_ / BM, C2_ / BN_T), 256, 0, stream>>>(
        y1, nullptr, w2t, b2, scale1, shift1, y2, C1_, C2_);
    stats_kernel<<<dim3(256), 256, 0, stream>>>(y2, sum2, ssq2, C2_, ROWS_ / 256);
    finalize_kernel<<<1, 256, 0, stream>>>(sum2, ssq2, g2, be2, scale2, shift2, C2_, 1.0f / ROWS_);

    bnrelu_store_kernel<<<dim3(ROWS_ * C2_ / 4 / 256), 256, 0, stream>>>(y2, scale2, shift2, out);
}

// Round 3
// 426.442 us; speedup vs baseline: 1.4775x; 1.4775x over previous
//
#include <hip/hip_runtime.h>
#include <hip/hip_bf16.h>

#define B_   8
#define N_   8192
#define S_   2048
#define D1_  128
#define D2_  256
#define CIN_ 384
#define C1_  256
#define C2_  128
#define ROWS_ (B_ * N_)   // 65536

typedef __attribute__((ext_vector_type(8))) short short8v;   // 8 bf16 (4 VGPRs)
typedef __attribute__((ext_vector_type(4))) float f32x4;     // MFMA acc

__device__ inline unsigned short f2bf(float x) {
    __hip_bfloat16 h = __float2bfloat16(x);   // RNE
    unsigned short u;
    __builtin_memcpy(&u, &h, 2);
    return u;
}
__device__ inline float bf2f(unsigned short u) {
    unsigned int x = ((unsigned int)u) << 16;
    float f;
    __builtin_memcpy(&f, &x, 4);
    return f;
}

// ---------------------------------------------------------------------------
// 3-NN: arithmetic BIT-IDENTICAL to round-2 (which matched the np reference
// with zero tie flips). Only the LDS layout changed (float4 broadcast reads).
// ---------------------------------------------------------------------------
__global__ __launch_bounds__(256) void nn3_kernel(
    const float* __restrict__ xyz1, const float* __restrict__ xyz2,
    int* __restrict__ nidx, float* __restrict__ nw)
{
#pragma clang fp contract(off)
    __shared__ float4 sp[S_];
    const int b = blockIdx.y;
    const int n = blockIdx.x * 256 + threadIdx.x;
    const float* x2 = xyz2 + (size_t)b * S_ * 3;
    for (int i = threadIdx.x; i < S_; i += 256) {
        float a = x2[i * 3 + 0], c = x2[i * 3 + 1], d = x2[i * 3 + 2];
        float4 q; q.x = a; q.y = c; q.z = d; q.w = (a * a + c * c) + d * d;
        sp[i] = q;
    }
    __syncthreads();
    const float* p = xyz1 + ((size_t)b * N_ + n) * 3;
    const float px = p[0], py = p[1], pz = p[2];
    const float r1 = (px * px + py * py) + pz * pz;
    float d1 = 3.4e38f, d2 = 3.4e38f, d3 = 3.4e38f;
    int i1 = 0, i2 = 0, i3 = 0;
    for (int s = 0; s < S_; ++s) {
        float4 q = sp[s];
        float dot = (px * q.x + py * q.y) + pz * q.z;
        float d = (r1 - 2.0f * dot) + q.w;
        if (d < d3) {
            if (d < d2) {
                d3 = d2; i3 = i2;
                if (d < d1) { d2 = d1; i2 = i1; d1 = d; i1 = s; }
                else        { d2 = d;  i2 = s; }
            } else { d3 = d; i3 = s; }
        }
    }
    float ra = 1.0f / (d1 + 1e-8f);
    float rb = 1.0f / (d2 + 1e-8f);
    float rc = 1.0f / (d3 + 1e-8f);
    float sum = (ra + rb) + rc;
    size_t o = ((size_t)b * N_ + n) * 3;
    nidx[o + 0] = i1; nidx[o + 1] = i2; nidx[o + 2] = i3;
    nw[o + 0] = ra / sum; nw[o + 1] = rb / sum; nw[o + 2] = rc / sum;
}

// f32 -> bf16 elementwise (weights)
__global__ void cvt_bf16_kernel(const float* __restrict__ src,
                                unsigned short* __restrict__ dst, int n)
{
    int i = blockIdx.x * 256 + threadIdx.x;
    if (i < n) dst[i] = f2bf(src[i]);
}

// ---------------------------------------------------------------------------
// Build A1 bf16 [ROWS][384] = concat(points1, three_interpolate(points2))
// ---------------------------------------------------------------------------
__global__ __launch_bounds__(256) void a1build_kernel(
    const float* __restrict__ p1, const float* __restrict__ p2,
    const int* __restrict__ nidx, const float* __restrict__ nw,
    unsigned short* __restrict__ A1)
{
    const int row = blockIdx.x;
    const int c = threadIdx.x;
    const int b = row >> 13;
    const int i0 = nidx[row * 3 + 0], i1 = nidx[row * 3 + 1], i2 = nidx[row * 3 + 2];
    const float w0 = nw[row * 3 + 0], w1 = nw[row * 3 + 1], w2 = nw[row * 3 + 2];
    const float* base = p2 + (size_t)b * S_ * D2_;
    float v = base[(size_t)i0 * D2_ + c] * w0
            + base[(size_t)i1 * D2_ + c] * w1
            + base[(size_t)i2 * D2_ + c] * w2;
    unsigned short* arow = A1 + (size_t)row * CIN_;
    arow[D1_ + c] = f2bf(v);
    if (c < D1_) arow[c] = f2bf(p1[(size_t)row * D1_ + c]);
}

// ---------------------------------------------------------------------------
// bf16 MFMA GEMM: out[row][n] = sum_k A[row][k]*W[n][k] + bias[n]
// 128x128 tile, 4 waves, each wave 64x64 (4x4 frags of 16x16x32).
// LDS subtile layout [kg][i][8]: element (kg,i,j) = X[i0+i][k0+kg*8+j],
// staged via global_load_lds width 16 (linear, wave-uniform dest).
// Fragment maps (m89/m97-verified): A,B idx=lane&15, k=8*(lane>>4)+j;
// D col=lane&15, row=4*(lane>>4)+reg.
// ---------------------------------------------------------------------------
template <int K, int COUT, int WRITE_BF16>
__global__ __launch_bounds__(256) void gemm_mfma_kernel(
    const unsigned short* __restrict__ A,   // [ROWS][K] bf16
    const unsigned short* __restrict__ W,   // [COUT][K] bf16
    const float* __restrict__ bias,         // [COUT]
    void* __restrict__ out)                 // [ROWS][COUT] bf16 or f32
{
    __shared__ unsigned short As[4][128][8];   // 8 KiB
    __shared__ unsigned short Bs[4][128][8];   // 8 KiB
    const int tid = threadIdx.x;
    const int wave = tid >> 6, lane = tid & 63;
    const int r0 = blockIdx.x * 128;
    const int n0 = blockIdx.y * 128;
    const int wr = wave >> 1, wc = wave & 1;
    const int kh = lane >> 4, l16 = lane & 15;

    f32x4 acc[4][4];
#pragma unroll
    for (int m = 0; m < 4; ++m)
#pragma unroll
        for (int n = 0; n < 4; ++n)
            acc[m][n] = (f32x4){0.f, 0.f, 0.f, 0.f};

    const int slotbase = wave * 64;   // wave-uniform LDS slot base

    for (int k0 = 0; k0 < K; k0 += 32) {
        __syncthreads();   // previous-iter LDS reads done before overwrite
#pragma unroll
        for (int p = 0; p < 2; ++p) {
            const int sb = p * 256 + slotbase;          // wave-uniform
            const int s = sb + lane;                    // per-lane slot
            const int kg = s >> 7, i = s & 127;
            const unsigned short* gA = A + (size_t)(r0 + i) * K + k0 + kg * 8;
            const unsigned short* gB = W + (size_t)(n0 + i) * K + k0 + kg * 8;
            __builtin_amdgcn_global_load_lds(
                (const __attribute__((address_space(1))) void*)gA,
                (__attribute__((address_space(3))) void*)(&As[0][0][0] + (size_t)sb * 8),
                16, 0, 0);
            __builtin_amdgcn_global_load_lds(
                (const __attribute__((address_space(1))) void*)gB,
                (__attribute__((address_space(3))) void*)(&Bs[0][0][0] + (size_t)sb * 8),
                16, 0, 0);
        }
        __syncthreads();   // vmcnt(0) drained by compiler before barrier

        short8v af[4], bf[4];
#pragma unroll
        for (int m = 0; m < 4; ++m)
            af[m] = *(const short8v*)&As[kh][wr * 64 + m * 16 + l16][0];
#pragma unroll
        for (int n = 0; n < 4; ++n)
            bf[n] = *(const short8v*)&Bs[kh][wc * 64 + n * 16 + l16][0];
#pragma unroll
        for (int m = 0; m < 4; ++m)
#pragma unroll
            for (int n = 0; n < 4; ++n)
                acc[m][n] = __builtin_amdgcn_mfma_f32_16x16x32_bf16(
                    af[m], bf[n], acc[m][n], 0, 0, 0);
    }

    // epilogue: +bias, store
#pragma unroll
    for (int n = 0; n < 4; ++n) {
        const int col = n0 + wc * 64 + n * 16 + l16;
        const float bv = bias[col];
#pragma unroll
        for (int m = 0; m < 4; ++m) {
            const int rowb = r0 + wr * 64 + m * 16 + kh * 4;
#pragma unroll
            for (int j = 0; j < 4; ++j) {
                const float v = acc[m][n][j] + bv;
                if (WRITE_BF16)
                    ((unsigned short*)out)[(size_t)(rowb + j) * COUT + col] = f2bf(v);
                else
                    ((float*)out)[(size_t)(rowb + j) * COUT + col] = v;
            }
        }
    }
}

// ---------------------------------------------------------------------------
// per-channel sum/sumsq over bf16 y [ROWS][256], LDS-reduced, 1 atomic/ch/blk
// ---------------------------------------------------------------------------
__global__ __launch_bounds__(256) void stats_bf16_kernel(
    const unsigned short* __restrict__ y, float* __restrict__ sums,
    float* __restrict__ ssqs, int rowsPerBlock)
{
    __shared__ float ls[C1_], lq[C1_];
    const int tid = threadIdx.x;
    ls[tid] = 0.f; lq[tid] = 0.f;
    __syncthreads();
    const int cg = tid & 31;          // channel octet: channels cg*8..cg*8+7
    const int rr = tid >> 5;          // 0..7
    const int r0 = blockIdx.x * rowsPerBlock;
    float s[8] = {0,0,0,0,0,0,0,0}, q[8] = {0,0,0,0,0,0,0,0};
    for (int r = r0 + rr; r < r0 + rowsPerBlock; r += 8) {
        short8v v = ((const short8v*)y)[(size_t)r * 32 + cg];
#pragma unroll
        for (int j = 0; j < 8; ++j) {
            float f = bf2f((unsigned short)v[j]);
            s[j] += f; q[j] += f * f;
        }
    }
#pragma unroll
    for (int j = 0; j < 8; ++j) {
        atomicAdd(&ls[cg * 8 + j], s[j]);
        atomicAdd(&lq[cg * 8 + j], q[j]);
    }
    __syncthreads();
    atomicAdd(&sums[tid], ls[tid]);
    atomicAdd(&ssqs[tid], lq[tid]);
}

// per-channel sum/sumsq over f32 y [ROWS][128]
__global__ __launch_bounds__(256) void stats_f32_kernel(
    const float* __restrict__ y, float* __restrict__ sums,
    float* __restrict__ ssqs, int rowsPerBlock)
{
    __shared__ float ls[C2_], lq[C2_];
    const int tid = threadIdx.x;
    if (tid < C2_) { ls[tid] = 0.f; lq[tid] = 0.f; }
    __syncthreads();
    const int cq = tid & 31;          // float4 group: channels cq*4..cq*4+3
    const int rr = tid >> 5;          // 0..7
    const int r0 = blockIdx.x * rowsPerBlock;
    float s[4] = {0,0,0,0}, q[4] = {0,0,0,0};
    for (int r = r0 + rr; r < r0 + rowsPerBlock; r += 8) {
        float4 v = ((const float4*)y)[(size_t)r * 32 + cq];
        s[0] += v.x; q[0] += v.x * v.x;
        s[1] += v.y; q[1] += v.y * v.y;
        s[2] += v.z; q[2] += v.z * v.z;
        s[3] += v.w; q[3] += v.w * v.w;
    }
#pragma unroll
    for (int j = 0; j < 4; ++j) {
        atomicAdd(&ls[cq * 4 + j], s[j]);
        atomicAdd(&lq[cq * 4 + j], q[j]);
    }
    __syncthreads();
    if (tid < C2_) {
        atomicAdd(&sums[tid], ls[tid]);
        atomicAdd(&ssqs[tid], lq[tid]);
    }
}

__global__ void finalize_kernel(const float* __restrict__ sums,
                                const float* __restrict__ ssqs,
                                const float* __restrict__ g,
                                const float* __restrict__ be,
                                float* __restrict__ scale,
                                float* __restrict__ shift, int C, float invCnt)
{
    int c = threadIdx.x;
    if (c < C) {
        float mu = sums[c] * invCnt;
        float var = ssqs[c] * invCnt - mu * mu;
        float sc = g[c] / sqrtf(var + 1e-5f);
        scale[c] = sc;
        shift[c] = be[c] - mu * sc;
    }
}

// y1 bf16 -> a2 bf16 : relu(y*scale+shift), 8 elems/thread
__global__ __launch_bounds__(256) void bnconv_kernel(
    const unsigned short* __restrict__ y, const float* __restrict__ scale,
    const float* __restrict__ shift, unsigned short* __restrict__ a2)
{
    const int i = blockIdx.x * 256 + threadIdx.x;    // short8 index
    const int c0 = (i * 8) & (C1_ - 1);
    short8v v = ((const short8v*)y)[i];
    short8v r;
#pragma unroll
    for (int j = 0; j < 8; ++j) {
        float f = bf2f((unsigned short)v[j]);
        f = fmaxf(fmaf(f, scale[c0 + j], shift[c0 + j]), 0.0f);
        r[j] = (short)f2bf(f);
    }
    ((short8v*)a2)[i] = r;
}

// final BN+ReLU, f32 out
__global__ __launch_bounds__(256) void bnrelu_store_kernel(
    const float* __restrict__ y, const float* __restrict__ scale,
    const float* __restrict__ shift, float* __restrict__ out)
{
    int i = blockIdx.x * 256 + threadIdx.x;   // float4 index
    float4 v = ((const float4*)y)[i];
    int o = (i * 4) & (C2_ - 1);
    float4 sc = *(const float4*)(scale + o);
    float4 sh = *(const float4*)(shift + o);
    float4 r;
    r.x = fmaxf(fmaf(v.x, sc.x, sh.x), 0.0f);
    r.y = fmaxf(fmaf(v.y, sc.y, sh.y), 0.0f);
    r.z = fmaxf(fmaf(v.z, sc.z, sh.z), 0.0f);
    r.w = fmaxf(fmaf(v.w, sc.w, sh.w), 0.0f);
    ((float4*)out)[i] = r;
}

extern "C" void kernel_launch(void* const* d_in, const int* in_sizes, int n_in,
                              void* d_out, int out_size, void* d_ws, size_t ws_size,
                              hipStream_t stream)
{
    const float* xyz1    = (const float*)d_in[0];
    const float* xyz2    = (const float*)d_in[1];
    const float* points1 = (const float*)d_in[2];
    const float* points2 = (const float*)d_in[3];
    const float* w1  = (const float*)d_in[4];
    const float* b1  = (const float*)d_in[5];
    const float* g1  = (const float*)d_in[6];
    const float* be1 = (const float*)d_in[7];
    const float* w2  = (const float*)d_in[8];
    const float* b2  = (const float*)d_in[9];
    const float* g2  = (const float*)d_in[10];
    const float* be2 = (const float*)d_in[11];
    float* out = (float*)d_out;

    char* w = (char*)d_ws;
    unsigned short* A1  = (unsigned short*)w;                    // 50,331,648 B
    unsigned short* y1b = (unsigned short*)(w + 50331648);       // 33,554,432 B
    unsigned short* a2b = (unsigned short*)(w + 83886080);       // 33,554,432 B
    float*          y2  = (float*)A1;                            // reuse region 0
    char* tail = w + 117440512;
    int*   nidx = (int*)tail;                                    // 786,432 B
    float* nw   = (float*)(tail + 786432);                       // 786,432 B
    unsigned short* w1b = (unsigned short*)(tail + 1572864);     // 196,608 B
    unsigned short* w2b = (unsigned short*)(tail + 1769472);     // 65,536 B
    float* sum1   = (float*)(tail + 1835008);
    float* ssq1   = sum1 + 256;
    float* sum2   = ssq1 + 256;
    float* ssq2   = sum2 + 128;
    float* scale1 = ssq2 + 128;
    float* shift1 = scale1 + 256;
    float* scale2 = shift1 + 256;
    float* shift2 = scale2 + 128;

    hipMemsetAsync(sum1, 0, (256 + 256 + 128 + 128) * sizeof(float), stream);

    cvt_bf16_kernel<<<dim3((C1_ * CIN_ + 255) / 256), 256, 0, stream>>>(w1, w1b, C1_ * CIN_);
    cvt_bf16_kernel<<<dim3((C2_ * C1_ + 255) / 256), 256, 0, stream>>>(w2, w2b, C2_ * C1_);

    nn3_kernel<<<dim3(N_ / 256, B_), 256, 0, stream>>>(xyz1, xyz2, nidx, nw);
    a1build_kernel<<<dim3(ROWS_), 256, 0, stream>>>(points1, points2, nidx, nw, A1);

    gemm_mfma_kernel<CIN_, C1_, 1><<<dim3(ROWS_ / 128, C1_ / 128), 256, 0, stream>>>(
        A1, w1b, b1, (void*)y1b);
    stats_bf16_kernel<<<dim3(64), 256, 0, stream>>>(y1b, sum1, ssq1, ROWS_ / 64);
    finalize_kernel<<<1, 256, 0, stream>>>(sum1, ssq1, g1, be1, scale1, shift1, C1_, 1.0f / ROWS_);
    bnconv_kernel<<<dim3(ROWS_ * C1_ / 8 / 256), 256, 0, stream>>>(y1b, scale1, shift1, a2b);

    gemm_mfma_kernel<C1_, C2_, 0><<<dim3(ROWS_ / 128, C2_ / 128), 256, 0, stream>>>(
        a2b, w2b, b2, (void*)y2);
    stats_f32_kernel<<<dim3(64), 256, 0, stream>>>(y2, sum2, ssq2, ROWS_ / 64);
    finalize_kernel<<<1, 256, 0, stream>>>(sum2, ssq2, g2, be2, scale2, shift2, C2_, 1.0f / ROWS_);

    bnrelu_store_kernel<<<dim3(ROWS_ * C2_ / 4 / 256), 256, 0, stream>>>(y2, scale2, shift2, out);
}

// Round 4
// 213.159 us; speedup vs baseline: 2.9558x; 2.0006x over previous
//
#include <hip/hip_runtime.h>
#include <hip/hip_bf16.h>

#define B_   8
#define N_   8192
#define S_   2048
#define D1_  128
#define D2_  256
#define CIN_ 384
#define C1_  256
#define C2_  128
#define ROWS_ (B_ * N_)   // 65536

typedef __attribute__((ext_vector_type(8))) short short8v;   // 8 bf16 (4 VGPRs)
typedef __attribute__((ext_vector_type(4))) float f32x4;     // MFMA acc

__device__ inline unsigned short f2bf(float x) {
    __hip_bfloat16 h = __float2bfloat16(x);   // RNE
    unsigned short u;
    __builtin_memcpy(&u, &h, 2);
    return u;
}
__device__ inline float bf2f(unsigned short u) {
    unsigned int x = ((unsigned int)u) << 16;
    float f;
    __builtin_memcpy(&f, &x, 4);
    return f;
}

// branchless sorted-top3 insert; strict `<` => existing (earlier) wins ties
__device__ inline void ins3(float d, int s,
                            float& e1, float& e2, float& e3,
                            int& j1, int& j2, int& j3)
{
    bool lt1 = d < e1, lt2 = d < e2, lt3 = d < e3;
    float nd3 = lt2 ? e2 : (lt3 ? d : e3);
    int   ni3 = lt2 ? j2 : (lt3 ? s : j3);
    float nd2 = lt1 ? e1 : (lt2 ? d : e2);
    int   ni2 = lt1 ? j1 : (lt2 ? s : j2);
    float nd1 = lt1 ? d : e1;
    int   ni1 = lt1 ? s : j1;
    e1 = nd1; e2 = nd2; e3 = nd3; j1 = ni1; j2 = ni2; j3 = ni3;
}

// ---------------------------------------------------------------------------
// 3-NN, 1024 threads/block: 256 queries x 4-way S-split, branchless inserts,
// LDS merge in chunk order (preserves top_k's lower-index-wins tie-break).
// Distance arithmetic BIT-IDENTICAL to the round-2/3 passing version.
// ---------------------------------------------------------------------------
__global__ __launch_bounds__(1024) void nn3_kernel(
    const float* __restrict__ xyz1, const float* __restrict__ xyz2,
    int* __restrict__ nidx, float* __restrict__ nw)
{
#pragma clang fp contract(off)
    __shared__ float4 sp[S_];                 // 32 KiB
    __shared__ float pd[4][256][3];           // 12 KiB
    __shared__ int   pi[4][256][3];           // 12 KiB
    const int tid = threadIdx.x;
    const int b = blockIdx.y;
    const int q = tid & 255;
    const int chunk = tid >> 8;               // 0..3
    const float* x2 = xyz2 + (size_t)b * S_ * 3;
    for (int i = tid; i < S_; i += 1024) {
        float a = x2[i * 3 + 0], c = x2[i * 3 + 1], d = x2[i * 3 + 2];
        float4 v; v.x = a; v.y = c; v.z = d; v.w = (a * a + c * c) + d * d;
        sp[i] = v;
    }
    __syncthreads();
    const int n = blockIdx.x * 256 + q;
    const float* p = xyz1 + ((size_t)b * N_ + n) * 3;
    const float px = p[0], py = p[1], pz = p[2];
    const float r1 = (px * px + py * py) + pz * pz;
    float d1 = 3.4e38f, d2 = 3.4e38f, d3 = 3.4e38f;
    int i1 = 0, i2 = 0, i3 = 0;
    const int s0 = chunk * 512;
#pragma unroll 4
    for (int k = 0; k < 512; ++k) {
        const int s = s0 + k;
        float4 qq = sp[s];
        float dot = (px * qq.x + py * qq.y) + pz * qq.z;
        float d = (r1 - 2.0f * dot) + qq.w;
        ins3(d, s, d1, d2, d3, i1, i2, i3);
    }
    pd[chunk][q][0] = d1; pd[chunk][q][1] = d2; pd[chunk][q][2] = d3;
    pi[chunk][q][0] = i1; pi[chunk][q][1] = i2; pi[chunk][q][2] = i3;
    __syncthreads();
    if (tid < 256) {
        float e1 = pd[0][tid][0], e2 = pd[0][tid][1], e3 = pd[0][tid][2];
        int   j1 = pi[0][tid][0], j2 = pi[0][tid][1], j3 = pi[0][tid][2];
#pragma unroll
        for (int c = 1; c < 4; ++c)
#pragma unroll
            for (int e = 0; e < 3; ++e)
                ins3(pd[c][tid][e], pi[c][tid][e], e1, e2, e3, j1, j2, j3);
        float ra = 1.0f / (e1 + 1e-8f);
        float rb = 1.0f / (e2 + 1e-8f);
        float rc = 1.0f / (e3 + 1e-8f);
        float sum = (ra + rb) + rc;
        size_t o = ((size_t)b * N_ + blockIdx.x * 256 + tid) * 3;
        nidx[o + 0] = j1; nidx[o + 1] = j2; nidx[o + 2] = j3;
        nw[o + 0] = ra / sum; nw[o + 1] = rb / sum; nw[o + 2] = rc / sum;
    }
}

// both weight tensors f32 -> bf16 in one launch
__global__ void cvtw_kernel(const float* __restrict__ w1, const float* __restrict__ w2,
                            unsigned short* __restrict__ w1b, unsigned short* __restrict__ w2b)
{
    int i = blockIdx.x * 256 + threadIdx.x;
    if (i < C1_ * CIN_) w1b[i] = f2bf(w1[i]);
    else {
        int j = i - C1_ * CIN_;
        if (j < C2_ * C1_) w2b[j] = f2bf(w2[j]);
    }
}

// ---------------------------------------------------------------------------
// Build A1 bf16 [ROWS][384] = concat(points1, three_interpolate(points2)).
// XCD-chunk swizzle: XCD x handles batch x exclusively -> its 4MB points2
// slab fits its private L2.
// ---------------------------------------------------------------------------
__global__ __launch_bounds__(256) void a1build_kernel(
    const float* __restrict__ p1, const float* __restrict__ p2,
    const int* __restrict__ nidx, const float* __restrict__ nw,
    unsigned short* __restrict__ A1)
{
    const int row = (blockIdx.x & 7) * N_ + (blockIdx.x >> 3);  // batch = xcd
    const int c = threadIdx.x;
    const int b = row >> 13;
    const int i0 = nidx[row * 3 + 0], i1 = nidx[row * 3 + 1], i2 = nidx[row * 3 + 2];
    const float w0 = nw[row * 3 + 0], w1 = nw[row * 3 + 1], w2 = nw[row * 3 + 2];
    const float* base = p2 + (size_t)b * S_ * D2_;
    float v = base[(size_t)i0 * D2_ + c] * w0
            + base[(size_t)i1 * D2_ + c] * w1
            + base[(size_t)i2 * D2_ + c] * w2;
    unsigned short* arow = A1 + (size_t)row * CIN_;
    arow[D1_ + c] = f2bf(v);
    if (c < D1_) arow[c] = f2bf(p1[(size_t)row * D1_ + c]);
}

// ---------------------------------------------------------------------------
// bf16 MFMA GEMM + fused bias + fused BN-stats epilogue.
// MODE 0: A staged via global_load_lds directly.
// MODE 1: A reg-staged with BN+ReLU applied in flight (scale/shift per k-chan).
// GRIDCOLS: col-blocks; XCD-chunk swizzle keeps a rowblock's colblocks on
// one XCD for A-tile L2 reuse.
// ---------------------------------------------------------------------------
template <int K, int COUT, int WRITE_BF16, int MODE, int GRIDCOLS>
__global__ __launch_bounds__(256) void gemm_mfma_kernel(
    const unsigned short* __restrict__ A,   // [ROWS][K] bf16
    const unsigned short* __restrict__ W,   // [COUT][K] bf16
    const float* __restrict__ bias,         // [COUT]
    const float* __restrict__ scale,        // [K]  (MODE 1)
    const float* __restrict__ shift,        // [K]  (MODE 1)
    void* __restrict__ out,                 // [ROWS][COUT] bf16 or f32
    float* __restrict__ sums, float* __restrict__ ssqs)
{
    __shared__ unsigned short As[4][128][8];   // 8 KiB
    __shared__ unsigned short Bs[4][128][8];   // 8 KiB
    __shared__ float csum[128], csq[128];
    const int tid = threadIdx.x;
    const int wave = tid >> 6, lane = tid & 63;
    // XCD-chunk swizzle
    const int chunkw = (blockIdx.x & 7) * (gridDim.x >> 3) + (blockIdx.x >> 3);
    const int r0 = (chunkw / GRIDCOLS) * 128;
    const int n0 = (chunkw % GRIDCOLS) * 128;
    const int wr = wave >> 1, wc = wave & 1;
    const int kh = lane >> 4, l16 = lane & 15;

    if (tid < 128) { csum[tid] = 0.f; csq[tid] = 0.f; }

    f32x4 acc[4][4];
#pragma unroll
    for (int m = 0; m < 4; ++m)
#pragma unroll
        for (int n = 0; n < 4; ++n)
            acc[m][n] = (f32x4){0.f, 0.f, 0.f, 0.f};

    const int slotbase = wave * 64;   // wave-uniform LDS slot base

    for (int k0 = 0; k0 < K; k0 += 32) {
        __syncthreads();
#pragma unroll
        for (int p = 0; p < 2; ++p) {
            const int sb = p * 256 + slotbase;          // wave-uniform
            const int s = sb + lane;                    // per-lane slot
            const int kg = s >> 7, i = s & 127;
            const unsigned short* gB = W + (size_t)(n0 + i) * K + k0 + kg * 8;
            __builtin_amdgcn_global_load_lds(
                (const __attribute__((address_space(1))) void*)gB,
                (__attribute__((address_space(3))) void*)(&Bs[0][0][0] + (size_t)sb * 8),
                16, 0, 0);
            if (MODE == 0) {
                const unsigned short* gA = A + (size_t)(r0 + i) * K + k0 + kg * 8;
                __builtin_amdgcn_global_load_lds(
                    (const __attribute__((address_space(1))) void*)gA,
                    (__attribute__((address_space(3))) void*)(&As[0][0][0] + (size_t)sb * 8),
                    16, 0, 0);
            } else {
                const int c0 = k0 + kg * 8;
                short8v v = *(const short8v*)(A + (size_t)(r0 + i) * K + c0);
                float4 sca = *(const float4*)(scale + c0);
                float4 scb = *(const float4*)(scale + c0 + 4);
                float4 sha = *(const float4*)(shift + c0);
                float4 shb = *(const float4*)(shift + c0 + 4);
                float sc[8] = {sca.x, sca.y, sca.z, sca.w, scb.x, scb.y, scb.z, scb.w};
                float sh[8] = {sha.x, sha.y, sha.z, sha.w, shb.x, shb.y, shb.z, shb.w};
                short8v r;
#pragma unroll
                for (int j = 0; j < 8; ++j) {
                    float f = bf2f((unsigned short)v[j]);
                    f = fmaxf(fmaf(f, sc[j], sh[j]), 0.0f);
                    r[j] = (short)f2bf(f);
                }
                *(short8v*)&As[kg][i][0] = r;
            }
        }
        __syncthreads();

        short8v af[4], bf[4];
#pragma unroll
        for (int m = 0; m < 4; ++m)
            af[m] = *(const short8v*)&As[kh][wr * 64 + m * 16 + l16][0];
#pragma unroll
        for (int n = 0; n < 4; ++n)
            bf[n] = *(const short8v*)&Bs[kh][wc * 64 + n * 16 + l16][0];
#pragma unroll
        for (int m = 0; m < 4; ++m)
#pragma unroll
            for (int n = 0; n < 4; ++n)
                acc[m][n] = __builtin_amdgcn_mfma_f32_16x16x32_bf16(
                    af[m], bf[n], acc[m][n], 0, 0, 0);
    }

    // epilogue: +bias, store, per-channel stats
#pragma unroll
    for (int n = 0; n < 4; ++n) {
        const int cl = wc * 64 + n * 16 + l16;       // 0..127 within tile
        const int col = n0 + cl;
        const float bv = bias[col];
        float s = 0.f, qs = 0.f;
#pragma unroll
        for (int m = 0; m < 4; ++m) {
            const int rowb = r0 + wr * 64 + m * 16 + kh * 4;
#pragma unroll
            for (int j = 0; j < 4; ++j) {
                const float v = acc[m][n][j] + bv;
                s += v; qs += v * v;
                if (WRITE_BF16)
                    ((unsigned short*)out)[(size_t)(rowb + j) * COUT + col] = f2bf(v);
                else
                    ((float*)out)[(size_t)(rowb + j) * COUT + col] = v;
            }
        }
        atomicAdd(&csum[cl], s);
        atomicAdd(&csq[cl], qs);
    }
    __syncthreads();
    if (tid < 128) {
        atomicAdd(&sums[n0 + tid], csum[tid]);
        atomicAdd(&ssqs[n0 + tid], csq[tid]);
    }
}

__global__ void finalize_kernel(const float* __restrict__ sums,
                                const float* __restrict__ ssqs,
                                const float* __restrict__ g,
                                const float* __restrict__ be,
                                float* __restrict__ scale,
                                float* __restrict__ shift, int C, float invCnt)
{
    int c = threadIdx.x;
    if (c < C) {
        float mu = sums[c] * invCnt;
        float var = ssqs[c] * invCnt - mu * mu;
        float sc = g[c] / sqrtf(var + 1e-5f);
        scale[c] = sc;
        shift[c] = be[c] - mu * sc;
    }
}

// final BN+ReLU, f32 out
__global__ __launch_bounds__(256) void bnrelu_store_kernel(
    const float* __restrict__ y, const float* __restrict__ scale,
    const float* __restrict__ shift, float* __restrict__ out)
{
    int i = blockIdx.x * 256 + threadIdx.x;   // float4 index
    float4 v = ((const float4*)y)[i];
    int o = (i * 4) & (C2_ - 1);
    float4 sc = *(const float4*)(scale + o);
    float4 sh = *(const float4*)(shift + o);
    float4 r;
    r.x = fmaxf(fmaf(v.x, sc.x, sh.x), 0.0f);
    r.y = fmaxf(fmaf(v.y, sc.y, sh.y), 0.0f);
    r.z = fmaxf(fmaf(v.z, sc.z, sh.z), 0.0f);
    r.w = fmaxf(fmaf(v.w, sc.w, sh.w), 0.0f);
    ((float4*)out)[i] = r;
}

extern "C" void kernel_launch(void* const* d_in, const int* in_sizes, int n_in,
                              void* d_out, int out_size, void* d_ws, size_t ws_size,
                              hipStream_t stream)
{
    const float* xyz1    = (const float*)d_in[0];
    const float* xyz2    = (const float*)d_in[1];
    const float* points1 = (const float*)d_in[2];
    const float* points2 = (const float*)d_in[3];
    const float* w1  = (const float*)d_in[4];
    const float* b1  = (const float*)d_in[5];
    const float* g1  = (const float*)d_in[6];
    const float* be1 = (const float*)d_in[7];
    const float* w2  = (const float*)d_in[8];
    const float* b2  = (const float*)d_in[9];
    const float* g2  = (const float*)d_in[10];
    const float* be2 = (const float*)d_in[11];
    float* out = (float*)d_out;

    char* w = (char*)d_ws;
    unsigned short* A1  = (unsigned short*)w;                    // 50,331,648 B
    unsigned short* y1b = (unsigned short*)(w + 50331648);       // 33,554,432 B
    float*          y2  = (float*)A1;                            // reuse region 0
    char* tail = w + 83886080;
    int*   nidx = (int*)tail;                                    // 786,432 B
    float* nw   = (float*)(tail + 786432);                       // 786,432 B
    unsigned short* w1b = (unsigned short*)(tail + 1572864);     // 196,608 B
    unsigned short* w2b = (unsigned short*)(tail + 1769472);     // 65,536 B
    float* sum1   = (float*)(tail + 1835008);
    float* ssq1   = sum1 + 256;
    float* sum2   = ssq1 + 256;
    float* ssq2   = sum2 + 128;
    float* scale1 = ssq2 + 128;
    float* shift1 = scale1 + 256;
    float* scale2 = shift1 + 256;
    float* shift2 = scale2 + 128;

    hipMemsetAsync(sum1, 0, (256 + 256 + 128 + 128) * sizeof(float), stream);

    cvtw_kernel<<<dim3((C1_ * CIN_ + C2_ * C1_ + 255) / 256), 256, 0, stream>>>(w1, w2, w1b, w2b);

    nn3_kernel<<<dim3(N_ / 256, B_), 1024, 0, stream>>>(xyz1, xyz2, nidx, nw);
    a1build_kernel<<<dim3(ROWS_), 256, 0, stream>>>(points1, points2, nidx, nw, A1);

    gemm_mfma_kernel<CIN_, C1_, 1, 0, 2><<<dim3(ROWS_ / 128 * 2), 256, 0, stream>>>(
        A1, w1b, b1, nullptr, nullptr, (void*)y1b, sum1, ssq1);
    finalize_kernel<<<1, 256, 0, stream>>>(sum1, ssq1, g1, be1, scale1, shift1, C1_, 1.0f / ROWS_);

    gemm_mfma_kernel<C1_, C2_, 0, 1, 1><<<dim3(ROWS_ / 128), 256, 0, stream>>>(
        y1b, w2b, b2, scale1, shift1, (void*)y2, sum2, ssq2);
    finalize_kernel<<<1, 256, 0, stream>>>(sum2, ssq2, g2, be2, scale2, shift2, C2_, 1.0f / ROWS_);

    bnrelu_store_kernel<<<dim3(ROWS_ * C2_ / 4 / 256), 256, 0, stream>>>(y2, scale2, shift2, out);
}